// Round 1
// baseline (685.614 us; speedup 1.0000x reference)
//
#include <hip/hip_runtime.h>
#include <math.h>

#define B_ 2
#define L_ 2048
#define DMODEL 2048
#define DINNER 4096
#define DSTATE 16
#define DCONV 4
#define DTRANK 128
#define NCHUNK 32
#define CLEN 64           // L_/NCHUNK
#define MROWS 4096        // B_*L_

typedef unsigned short ushort_t;
typedef unsigned int uint_t;
typedef __attribute__((ext_vector_type(8))) short bf16x8;
typedef __attribute__((ext_vector_type(4))) float floatx4;

__device__ __forceinline__ float sigmoidf_(float x){ return 1.f/(1.f+__expf(-x)); }
__device__ __forceinline__ ushort_t f2bf(float f){
    uint_t u = __builtin_bit_cast(uint_t, f);
    return (ushort_t)((u + 0x7FFFu + ((u >> 16) & 1u)) >> 16);
}
__device__ __forceinline__ float bf2f(ushort_t h){
    return __builtin_bit_cast(float, (uint_t)h << 16);
}
__device__ __forceinline__ float fast_exp2(float x){
#if __has_builtin(__builtin_amdgcn_exp2f)
    return __builtin_amdgcn_exp2f(x);
#else
    return exp2f(x);
#endif
}
#define LOG2E 1.44269504088896f

#define GLD_LDS16(g, l) __builtin_amdgcn_global_load_lds( \
    (const __attribute__((address_space(1))) void*)(g),   \
    (__attribute__((address_space(3))) void*)(l), 16, 0, 0)

// ---------------------------------------------------------------------------
// 128x128 bf16 MFMA GEMM (m97 structure) — kept for x_proj (split-K, N=256)
// and dt_proj (K=128). See previous version's comments.
// ---------------------------------------------------------------------------
template<int OUTBF, int EPI, int SPLIT, int KSPLIT>
__global__ __launch_bounds__(256)
void gemm_mfma(const ushort_t* __restrict__ Aptr, int lda,
               const ushort_t* __restrict__ W, int ldw,
               void* __restrict__ Cptr, void* __restrict__ C2,
               int ldc, int Klen,
               const float* __restrict__ bias)
{
    __shared__ ushort_t lsA[128*64];
    __shared__ ushort_t lsW[128*64];
    const int tid  = threadIdx.x;
    const int row0 = blockIdx.x * 128;
    const int col0 = blockIdx.y * 128;
    const int koff = KSPLIT ? blockIdx.z * Klen : 0;
    const int lane = tid & 63;
    const int wv   = tid >> 6;
    const int wm   = (wv >> 1) * 64;
    const int wn   = (wv & 1) * 64;
    const int lr   = lane & 15;
    const int lq   = lane >> 4;

    floatx4 acc[4][4];
    #pragma unroll
    for(int i=0;i<4;i++)
        #pragma unroll
        for(int j=0;j<4;j++)
            #pragma unroll
            for(int r=0;r<4;r++) acc[i][j][r] = 0.f;

    for(int k0 = koff; k0 < koff + Klen; k0 += 64){
        #pragma unroll
        for(int it=0; it<4; it++){
            const int slot = it*256 + tid;
            const int row  = slot >> 3;
            const int p    = slot & 7;
            const int s    = p ^ (row & 7);
            const ushort_t* gw = W    + (size_t)(col0 + row)*ldw + k0 + s*8;
            const ushort_t* ga = Aptr + (size_t)(row0 + row)*lda + k0 + s*8;
            GLD_LDS16(gw, &lsW[slot*8]);
            GLD_LDS16(ga, &lsA[slot*8]);
        }
        __syncthreads();

        #pragma unroll
        for(int kk=0; kk<2; kk++){
            bf16x8 af[4], bw[4];
            #pragma unroll
            for(int i=0;i<4;i++){
                const int ra = wm + i*16 + lr;
                const int rb = wn + i*16 + lr;
                af[i] = *(const bf16x8*)&lsA[ra*64 + (((kk*4+lq) ^ (ra&7))*8)];
                bw[i] = *(const bf16x8*)&lsW[rb*64 + (((kk*4+lq) ^ (rb&7))*8)];
            }
            #pragma unroll
            for(int i=0;i<4;i++)
                #pragma unroll
                for(int j=0;j<4;j++)
                    acc[i][j] = __builtin_amdgcn_mfma_f32_16x16x32_bf16(af[i], bw[j], acc[i][j], 0, 0, 0);
        }
        __syncthreads();
    }

    void* dst = Cptr;
    int cbase = col0;
    if (SPLIT && col0 >= ldc){ dst = C2; cbase = col0 - ldc; }
    const size_t zoff = KSPLIT ? (size_t)blockIdx.z * MROWS * ldc : 0;

    #pragma unroll
    for(int i=0;i<4;i++){
        #pragma unroll
        for(int r=0;r<4;r++){
            const int row = row0 + wm + i*16 + lq*4 + r;
            #pragma unroll
            for(int j=0;j<4;j++){
                const int col = cbase + wn + j*16 + lr;
                float v = acc[i][j][r];
                if (EPI){
                    v += bias[col];
                    v = (v > 20.f) ? v : log1pf(expf(v));
                }
                if (OUTBF) ((ushort_t*)dst)[(size_t)row*ldc + col] = f2bf(v);
                else       ((float*)  dst)[zoff + (size_t)row*ldc + col] = v;
            }
        }
    }
}

// ---------------------------------------------------------------------------
// 256x256 8-phase bf16 GEMM (m201-style, T2+T3+T4+T5): C[M,N]=A[M,K]*W[N,K]^T
// 512 threads = 8 waves (2M x 4N); per-wave output 128x64; BK=64.
// LDS 128 KiB = 2 dbuf x {A,B} x {Kh0,Kh1} x (256 rows x 32 ushorts).
// K-half staging: 4 half-tiles/K-tile, one issued per phase, consumed 6
// phases later -> counted s_waitcnt vmcnt(8) fused with s_barrier (never 0
// in steady state; drain 8 -> 4 -> 0 at tail).
// Swizzle: chunk f (16B) of double-row dr holds (row 2*dr+b, K-seg s) with
// (b*4+s) = f ^ (dr&7). gload_lds dest is linear (g*16B); source is per-lane
// pre-swizzled (guide rule #21 pattern c). ds_read_b128: lane(lr,lq) reads
// slot f = ((lr&1)*4+lq) ^ (lr>>1): 16-lane groups hit 8 distinct 16B slots
// (all 32 banks, 2-way = free). Assumes M%256==0, N%256==0, NT=Klen/64 >= 2.
// ---------------------------------------------------------------------------
template<int OUTBF, int SPLIT, int KSPLIT>
__global__ __launch_bounds__(512, 2)
void gemm_256(const ushort_t* __restrict__ Aptr, int lda,
              const ushort_t* __restrict__ W, int ldw,
              void* __restrict__ Cptr, void* __restrict__ C2,
              int ldc, int Klen)
{
    __shared__ ushort_t lds[2][2][2][8192];   // [dbuf][A/B][khalf][256x32]
    const int tid  = threadIdx.x;
    const int row0 = blockIdx.x * 256;
    const int col0 = blockIdx.y * 256;
    const int koff = KSPLIT ? blockIdx.z * Klen : 0;
    const int NT   = Klen >> 6;
    const int lane = tid & 63;
    const int wv   = tid >> 6;
    const int wr   = wv >> 2;          // 0..1 : M half (128 rows)
    const int wc   = wv & 3;           // 0..3 : N quarter (64 cols)
    const int lr   = lane & 15;
    const int lq   = lane >> 4;

    // staging slots: chunk g = it*512+tid in [0,1024): dr=g>>3, f=g&7,
    // u=f^(dr&7) -> source row 2*dr+(u>>2), source K-seg (u&3)*8.
    int sdst0, sdst1;
    const ushort_t *aS0, *aS1, *wS0, *wS1;
    {
        const int g0 = tid,     dr0 = g0 >> 3, f0 = g0 & 7;
        const int g1 = 512+tid, dr1 = g1 >> 3, f1 = g1 & 7;
        const int u0 = f0 ^ (dr0 & 7), u1 = f1 ^ (dr1 & 7);
        const int r0s = dr0*2 + (u0 >> 2), c0s = (u0 & 3)*8;
        const int r1s = dr1*2 + (u1 >> 2), c1s = (u1 & 3)*8;
        sdst0 = g0*8; sdst1 = g1*8;
        aS0 = Aptr + (size_t)(row0 + r0s)*lda + c0s;
        aS1 = Aptr + (size_t)(row0 + r1s)*lda + c1s;
        wS0 = W    + (size_t)(col0 + r0s)*ldw + c0s;
        wS1 = W    + (size_t)(col0 + r1s)*ldw + c1s;
    }
    #define STG_A(kc, reg) { GLD_LDS16(aS0 + (kc), &(reg)[sdst0]); \
                             GLD_LDS16(aS1 + (kc), &(reg)[sdst1]); }
    #define STG_W(kc, reg) { GLD_LDS16(wS0 + (kc), &(reg)[sdst0]); \
                             GLD_LDS16(wS1 + (kc), &(reg)[sdst1]); }

    // ds_read base (ushort units): (a + i*8)*64 + f*8 = base + i*512
    const int frd = ((lr & 1)*4 + lq) ^ (lr >> 1);
    const int aA  = (wr*64 + (lr >> 1))*64 + frd*8;
    const int aB  = (wc*32 + (lr >> 1))*64 + frd*8;

    floatx4 acc[8][4];
    #pragma unroll
    for(int i=0;i<8;i++)
        #pragma unroll
        for(int j=0;j<4;j++)
            #pragma unroll
            for(int r=0;r<4;r++) acc[i][j][r] = 0.f;

    // prologue: issue A0(0) B0(0) A1(0) B1(0) A0(1) B0(1); wait oldest 2
    // half-tiles (Kh0 of tile 0) -> 8 loads still in flight.
    STG_A(koff,    lds[0][0][0]);
    STG_W(koff,    lds[0][1][0]);
    STG_A(koff+32, lds[0][0][1]);
    STG_W(koff+32, lds[0][1][1]);
    STG_A(koff+64, lds[1][0][0]);
    STG_W(koff+64, lds[1][1][0]);
    asm volatile("s_waitcnt vmcnt(8)\ns_barrier" ::: "memory");

    for(int t=0; t<NT; ++t){
        const int c = t & 1;
        const ushort_t* LA0 = lds[c][0][0];
        const ushort_t* LB0 = lds[c][1][0];
        const ushort_t* LA1 = lds[c][0][1];
        const ushort_t* LB1 = lds[c][1][1];
        const int kt1 = koff + (t+1)*64;
        const int kt2 = koff + (t+2)*64;
        bf16x8 af[8], b0, b1;

        // ---- phase 0: Kh0 x j-half0; prefetch A.Kh1(t+1) -> buf c^1 ----
        #pragma unroll
        for(int i=0;i<8;i++) af[i] = *(const bf16x8*)&LA0[aA + i*512];
        b0 = *(const bf16x8*)&LB0[aB];
        b1 = *(const bf16x8*)&LB0[aB + 512];
        if (t+1 < NT) STG_A(kt1+32, lds[c^1][0][1]);
        __builtin_amdgcn_s_barrier();
        asm volatile("s_waitcnt lgkmcnt(0)" ::: "memory");
        __builtin_amdgcn_s_setprio(1);
        #pragma unroll
        for(int i=0;i<8;i++){
            acc[i][0] = __builtin_amdgcn_mfma_f32_16x16x32_bf16(af[i], b0, acc[i][0],0,0,0);
            acc[i][1] = __builtin_amdgcn_mfma_f32_16x16x32_bf16(af[i], b1, acc[i][1],0,0,0);
        }
        __builtin_amdgcn_s_setprio(0);
        __builtin_amdgcn_s_barrier();

        // ---- phase 1: Kh0 x j-half1; prefetch B.Kh1(t+1) ----
        b0 = *(const bf16x8*)&LB0[aB + 1024];
        b1 = *(const bf16x8*)&LB0[aB + 1536];
        if (t+1 < NT) STG_W(kt1+32, lds[c^1][1][1]);
        __builtin_amdgcn_s_barrier();
        asm volatile("s_waitcnt lgkmcnt(0)" ::: "memory");
        __builtin_amdgcn_s_setprio(1);
        #pragma unroll
        for(int i=0;i<8;i++){
            acc[i][2] = __builtin_amdgcn_mfma_f32_16x16x32_bf16(af[i], b0, acc[i][2],0,0,0);
            acc[i][3] = __builtin_amdgcn_mfma_f32_16x16x32_bf16(af[i], b1, acc[i][3],0,0,0);
        }
        __builtin_amdgcn_s_setprio(0);
        // W1: guarantee Kh1(t) landed (issued 6 phases ago); 4 newer
        // half-tiles stay in flight. Fused wait+barrier => collective.
        if (t+1 < NT) asm volatile("s_waitcnt vmcnt(8)\ns_barrier" ::: "memory");
        else          asm volatile("s_waitcnt vmcnt(0)\ns_barrier" ::: "memory");

        // ---- phase 2: Kh1 x j-half0; prefetch A.Kh0(t+2) -> buf c ----
        #pragma unroll
        for(int i=0;i<8;i++) af[i] = *(const bf16x8*)&LA1[aA + i*512];
        b0 = *(const bf16x8*)&LB1[aB];
        b1 = *(const bf16x8*)&LB1[aB + 512];
        if (t+2 < NT) STG_A(kt2, lds[c][0][0]);
        __builtin_amdgcn_s_barrier();
        asm volatile("s_waitcnt lgkmcnt(0)" ::: "memory");
        __builtin_amdgcn_s_setprio(1);
        #pragma unroll
        for(int i=0;i<8;i++){
            acc[i][0] = __builtin_amdgcn_mfma_f32_16x16x32_bf16(af[i], b0, acc[i][0],0,0,0);
            acc[i][1] = __builtin_amdgcn_mfma_f32_16x16x32_bf16(af[i], b1, acc[i][1],0,0,0);
        }
        __builtin_amdgcn_s_setprio(0);
        __builtin_amdgcn_s_barrier();

        // ---- phase 3: Kh1 x j-half1; prefetch B.Kh0(t+2) ----
        b0 = *(const bf16x8*)&LB1[aB + 1024];
        b1 = *(const bf16x8*)&LB1[aB + 1536];
        if (t+2 < NT) STG_W(kt2, lds[c][1][0]);
        __builtin_amdgcn_s_barrier();
        asm volatile("s_waitcnt lgkmcnt(0)" ::: "memory");
        __builtin_amdgcn_s_setprio(1);
        #pragma unroll
        for(int i=0;i<8;i++){
            acc[i][2] = __builtin_amdgcn_mfma_f32_16x16x32_bf16(af[i], b0, acc[i][2],0,0,0);
            acc[i][3] = __builtin_amdgcn_mfma_f32_16x16x32_bf16(af[i], b1, acc[i][3],0,0,0);
        }
        __builtin_amdgcn_s_setprio(0);
        // W2: guarantee Kh0(t+1) landed. Steady 8 in flight; tail 4 -> none.
        if (t+2 < NT)      asm volatile("s_waitcnt vmcnt(8)\ns_barrier" ::: "memory");
        else if (t+1 < NT) asm volatile("s_waitcnt vmcnt(4)\ns_barrier" ::: "memory");
        else               asm volatile("s_barrier" ::: "memory");
    }
    #undef STG_A
    #undef STG_W

    void* dst = Cptr;
    int cb = col0;
    if (SPLIT && col0 >= ldc){ dst = C2; cb = col0 - ldc; }
    const size_t zoff = KSPLIT ? (size_t)blockIdx.z * MROWS * ldc : 0;
    const int rbase = row0 + wr*128 + lq*4;
    const int cbase = cb + wc*64 + lr;
    #pragma unroll
    for(int i=0;i<8;i++){
        #pragma unroll
        for(int r=0;r<4;r++){
            const int row = rbase + i*16 + r;
            #pragma unroll
            for(int j=0;j<4;j++){
                const int col = cbase + j*16;
                const float v = acc[i][j][r];
                if (OUTBF) ((ushort_t*)dst)[(size_t)row*ldc + col] = f2bf(v);
                else       ((float*)dst)[zoff + (size_t)row*ldc + col] = v;
            }
        }
    }
}

// pairwise reduce of 2 split-K f32 partial planes
__global__ __launch_bounds__(256)
void reduce2(const float* __restrict__ P, float* __restrict__ out, int n4)
{
    const int i = blockIdx.x*256 + threadIdx.x;
    if (i < n4){
        float4 a = *(const float4*)(P + (size_t)i*4);
        float4 b = *(const float4*)(P + (size_t)(i + n4)*4);
        float4 r; r.x=a.x+b.x; r.y=a.y+b.y; r.z=a.z+b.z; r.w=a.w+b.w;
        *(float4*)(out + (size_t)i*4) = r;
    }
}

// f32 -> bf16 cast, 4 elems/thread
__global__ __launch_bounds__(256)
void cvt_bf16(const float* __restrict__ in, ushort_t* __restrict__ out, int n4)
{
    const int i = blockIdx.x*256 + threadIdx.x;
    if (i < n4){
        float4 v = *(const float4*)(in + (size_t)i*4);
        union { ushort_t u[4]; uint2 q; } p;
        p.u[0]=f2bf(v.x); p.u[1]=f2bf(v.y); p.u[2]=f2bf(v.z); p.u[3]=f2bf(v.w);
        *(uint2*)(out + (size_t)i*4) = p.q;
    }
}

// w_xproj 160x4096 f32 -> 256x4096 bf16, rows 160..255 zero
__global__ __launch_bounds__(256)
void cvt_pad256(const float* __restrict__ in, ushort_t* __restrict__ out)
{
    const int i = blockIdx.x*256 + threadIdx.x;
    const int row = i >> 10;
    const int c4  = i & 1023;
    union { ushort_t u[4]; uint2 q; } p;
    if (row < 160){
        float4 v = *(const float4*)(in + (size_t)row*4096 + c4*4);
        p.u[0]=f2bf(v.x); p.u[1]=f2bf(v.y); p.u[2]=f2bf(v.z); p.u[3]=f2bf(v.w);
    } else { p.u[0]=0; p.u[1]=0; p.u[2]=0; p.u[3]=0; }
    *(uint2*)(out + (size_t)i*4) = p.q;
}

// reduce split-K partials P[8][4096][256] -> xdbl f32 (ld 160) + dtlo bf16 (ld 128)
__global__ __launch_bounds__(256)
void reduce_xproj(const float* __restrict__ P, float* __restrict__ xdbl,
                  ushort_t* __restrict__ dtlo)
{
    const int row = blockIdx.x;
    const int col = threadIdx.x;
    float s = 0.f;
    #pragma unroll
    for(int z=0; z<8; z++)
        s += P[(size_t)z*MROWS*256 + (size_t)row*256 + col];
    if (col < 160) xdbl[(size_t)row*160 + col] = s;
    if (col < DTRANK) dtlo[(size_t)row*DTRANK + col] = f2bf(s);
}

// depthwise causal conv (k=4) + bias + silu, bf16 in/out
__global__ __launch_bounds__(256)
void conv_silu_bf(const ushort_t* __restrict__ xb, const float* __restrict__ w,
                  const float* __restrict__ bias, ushort_t* __restrict__ xc)
{
    const int gid = blockIdx.x*256 + threadIdx.x;
    const int d = gid & (DINNER-1);
    const int t = gid >> 12;
    const int l = t & (L_-1);
    float s = bias[d];
    #pragma unroll
    for(int j=0;j<DCONV;j++){
        const int ll = l - (DCONV-1) + j;
        if (ll >= 0)
            s = fmaf(bf2f(xb[(size_t)(t-(DCONV-1)+j)*DINNER + d]), w[d*DCONV+j], s);
    }
    xc[(size_t)t*DINNER + d] = f2bf(s * sigmoidf_(s));
}

// ---- chunked scan, one thread per channel d, 16 states in registers ----
__global__ __launch_bounds__(256)
void scan_phase1(const ushort_t* __restrict__ dt_bf,
                 const ushort_t* __restrict__ xconv,
                 const float* __restrict__ xdbl,
                 const float* __restrict__ A_log,
                 float* __restrict__ sc_h, float* __restrict__ sc_S)
{
    const int tid = threadIdx.x;
    const int d = blockIdx.x*256 + tid;
    const int chunk = blockIdx.y;
    const int b = blockIdx.z;
    const int l0 = chunk*CLEN;

    __shared__ float Bs[CLEN][DSTATE];
    for(int i=tid; i<CLEN*DSTATE; i+=256){
        const int row = i >> 4, n = i & 15;
        Bs[row][n] = xdbl[(size_t)(b*L_ + l0 + row)*160 + DTRANK + n];
    }
    float negA[DSTATE];
    #pragma unroll
    for(int n=0;n<DSTATE;n++) negA[n] = -expf(A_log[d*DSTATE + n]) * LOG2E;
    __syncthreads();

    float h[DSTATE], S[DSTATE];
    #pragma unroll
    for(int n=0;n<DSTATE;n++){ h[n]=0.f; S[n]=0.f; }

    size_t idx = (size_t)(b*L_ + l0)*DINNER + d;
    float dt_c = bf2f(dt_bf[idx]);
    float xv_c = bf2f(xconv[idx]);
    for(int l=0;l<CLEN;l++){
        float dt_n = 0.f, xv_n = 0.f;
        if (l+1 < CLEN){
            dt_n = bf2f(dt_bf[idx + DINNER]);
            xv_n = bf2f(xconv[idx + DINNER]);
        }
        const float dx = dt_c * xv_c;
        #pragma unroll
        for(int n=0;n<DSTATE;n++){
            const float t = dt_c * negA[n];
            S[n] += t;
            h[n] = fmaf(h[n], fast_exp2(t), dx*Bs[l][n]);
        }
        dt_c = dt_n; xv_c = xv_n;
        idx += DINNER;
    }
    const size_t o = (size_t)(b*NCHUNK + chunk)*DSTATE*DINNER + d;
    #pragma unroll
    for(int n=0;n<DSTATE;n++){
        sc_h[o + (size_t)n*DINNER] = h[n];
        sc_S[o + (size_t)n*DINNER] = S[n];
    }
}

__global__ __launch_bounds__(256)
void scan_phase2(float* __restrict__ sc_h, const float* __restrict__ sc_S)
{
    const int gid = blockIdx.x*256 + threadIdx.x;
    const int b = gid / (DSTATE*DINNER);
    const int rem = gid - b*DSTATE*DINNER;
    const size_t base = (size_t)b*NCHUNK*DSTATE*DINNER + rem;
    float H = 0.f;
    #pragma unroll
    for(int c=0;c<NCHUNK;c++){
        const size_t idx = base + (size_t)c*DSTATE*DINNER;
        const float he = sc_h[idx];
        const float S  = sc_S[idx];
        sc_h[idx] = H;
        H = fmaf(fast_exp2(S), H, he);
    }
}

__global__ __launch_bounds__(256)
void scan_phase3(const ushort_t* __restrict__ dt_bf,
                 const ushort_t* __restrict__ xconv,
                 const float* __restrict__ xdbl,
                 const ushort_t* __restrict__ z_bf,
                 const float* __restrict__ A_log,
                 const float* __restrict__ Dvec,
                 const float* __restrict__ sc_h,
                 ushort_t* __restrict__ y_bf)
{
    const int tid = threadIdx.x;
    const int d = blockIdx.x*256 + tid;
    const int chunk = blockIdx.y;
    const int b = blockIdx.z;
    const int l0 = chunk*CLEN;

    __shared__ float BCs[CLEN][2*DSTATE];
    for(int i=tid; i<CLEN*2*DSTATE; i+=256){
        const int row = i >> 5, c = i & 31;
        BCs[row][c] = xdbl[(size_t)(b*L_ + l0 + row)*160 + DTRANK + c];
    }
    float negA[DSTATE];
    #pragma unroll
    for(int n=0;n<DSTATE;n++) negA[n] = -expf(A_log[d*DSTATE + n]) * LOG2E;
    const float Dv = Dvec[d];
    float h[DSTATE];
    const size_t o = (size_t)(b*NCHUNK + chunk)*DSTATE*DINNER + d;
    #pragma unroll
    for(int n=0;n<DSTATE;n++) h[n] = sc_h[o + (size_t)n*DINNER];
    __syncthreads();

    size_t idx = (size_t)(b*L_ + l0)*DINNER + d;
    float dt_c = bf2f(dt_bf[idx]);
    float xv_c = bf2f(xconv[idx]);
    float zv_c = bf2f(z_bf[idx]);
    for(int l=0;l<CLEN;l++){
        float dt_n = 0.f, xv_n = 0.f, zv_n = 0.f;
        if (l+1 < CLEN){
            dt_n = bf2f(dt_bf[idx + DINNER]);
            xv_n = bf2f(xconv[idx + DINNER]);
            zv_n = bf2f(z_bf[idx + DINNER]);
        }
        const float dx = dt_c * xv_c;
        float y = 0.f;
        #pragma unroll
        for(int n=0;n<DSTATE;n++){
            const float t = dt_c * negA[n];
            h[n] = fmaf(h[n], fast_exp2(t), dx*BCs[l][n]);
            y = fmaf(h[n], BCs[l][DSTATE+n], y);
        }
        const float g = zv_c * sigmoidf_(zv_c);
        y_bf[idx] = f2bf(fmaf(xv_c, Dv, y) * g);
        dt_c = dt_n; xv_c = xv_n; zv_c = zv_n;
        idx += DINNER;
    }
}

extern "C" void kernel_launch(void* const* d_in, const int* in_sizes, int n_in,
                              void* d_out, int out_size, void* d_ws, size_t ws_size,
                              hipStream_t stream) {
    const float* hs      = (const float*)d_in[0];
    const float* w_in    = (const float*)d_in[1];
    const float* w_conv  = (const float*)d_in[2];
    const float* b_conv  = (const float*)d_in[3];
    const float* w_xproj = (const float*)d_in[4];
    const float* w_dt    = (const float*)d_in[5];
    const float* b_dt    = (const float*)d_in[6];
    const float* w_out   = (const float*)d_in[7];
    const float* A_log   = (const float*)d_in[8];
    const float* Dvec    = (const float*)d_in[9];
    float* out = (float*)d_out;

    // workspace layout (peak 176 MiB):
    // [0,32M)    x_bf -> after conv: xdbl@0, wx_bf@4M, dtlo@6M, wdt@7M, sc_h@8M(16M)
    // [32M,64M)  z_bf (live to phase3)    -> after phase3: out_proj partials lo
    // [64M,96M)  xconv (live to phase3)   -> after phase3: out_proj partials hi
    // [96M,128M) wi_bf -> after in_proj: dt_bf
    // [128M,144M) hs_bf -> after in_proj: sc_S -> after phase2: wo_bf
    // [144M,176M) y_bf  (also x_proj split-K partials, dead before phase3)
    char* base = (char*)d_ws;
    ushort_t* x_bf   = (ushort_t*)(base);
    float*    xdbl   = (float*)   (base);
    ushort_t* wx_bf  = (ushort_t*)(base + (4u<<20));
    ushort_t* dtlo_bf= (ushort_t*)(base + (6u<<20));
    ushort_t* wdt_bf = (ushort_t*)(base + (7u<<20));
    float*    sc_h   = (float*)   (base + (8u<<20));
    ushort_t* z_bf   = (ushort_t*)(base + (32u<<20));
    float*    op_par = (float*)   (base + (32u<<20));  // 2*4096*2048*4 = 64 MiB
    ushort_t* xconv  = (ushort_t*)(base + (64u<<20));
    ushort_t* wi_bf  = (ushort_t*)(base + (96u<<20));
    ushort_t* dt_bf  = (ushort_t*)(base + (96u<<20));
    ushort_t* hs_bf  = (ushort_t*)(base + (128u<<20));
    float*    sc_S   = (float*)   (base + (128u<<20));
    ushort_t* wo_bf  = (ushort_t*)(base + (128u<<20));
    float*    xp_par = (float*)   (base + (144u<<20));  // 8*4096*256*4 = 32 MiB
    ushort_t* y_bf   = (ushort_t*)(base + (144u<<20));

    dim3 blk(256);
    dim3 blk5(512);

    // convert activations + in_proj weights to bf16
    cvt_bf16<<<dim3(MROWS*DMODEL/4/256), blk, 0, stream>>>(hs, hs_bf, MROWS*DMODEL/4);
    cvt_bf16<<<dim3(2*DINNER*DMODEL/4/256), blk, 0, stream>>>(w_in, wi_bf, 2*DINNER*DMODEL/4);

    // fused in_proj (8-phase 256^2): N=8192, split-store x half / z half
    gemm_256<1,1,0><<<dim3(MROWS/256, 2*DINNER/256), blk5, 0, stream>>>(
        hs_bf, DMODEL, wi_bf, DMODEL, x_bf, z_bf, DINNER, DMODEL);

    // conv + silu -> xconv bf16 (x_bf region becomes free after this)
    conv_silu_bf<<<dim3((size_t)MROWS*DINNER/256), blk, 0, stream>>>(x_bf, w_conv, b_conv, xconv);

    // x_proj: split-K x 8 into f32 partials, then reduce (+fused dtlo cvt)
    cvt_pad256<<<dim3(256*4096/4/256), blk, 0, stream>>>(w_xproj, wx_bf);
    gemm_mfma<0,0,0,1><<<dim3(MROWS/128, 2, 8), blk, 0, stream>>>(
        xconv, DINNER, wx_bf, DINNER, xp_par, nullptr, 256, DINNER/8, nullptr);
    reduce_xproj<<<dim3(MROWS), blk, 0, stream>>>(xp_par, xdbl, dtlo_bf);

    // dt_proj + bias + softplus -> dt_bf (overwrites dead wi_bf region)
    cvt_bf16<<<dim3(DINNER*DTRANK/4/256), blk, 0, stream>>>(w_dt, wdt_bf, DINNER*DTRANK/4);
    gemm_mfma<1,1,0,0><<<dim3(MROWS/128, DINNER/128), blk, 0, stream>>>(
        dtlo_bf, DTRANK, wdt_bf, DTRANK, dt_bf, nullptr, DINNER, DTRANK, b_dt);

    // chunked selective scan (thread-per-channel, coalesced)
    dim3 sgrid(DINNER/256, NCHUNK, B_);
    scan_phase1<<<sgrid, blk, 0, stream>>>(dt_bf, xconv, xdbl, A_log, sc_h, sc_S);
    scan_phase2<<<dim3(B_*DSTATE*DINNER/256), blk, 0, stream>>>(sc_h, sc_S);

    // w_out conversion (sc_S dead after phase2; reuse its region)
    cvt_bf16<<<dim3(DMODEL*DINNER/4/256), blk, 0, stream>>>(w_out, wo_bf, DMODEL*DINNER/4);

    scan_phase3<<<sgrid, blk, 0, stream>>>(dt_bf, xconv, xdbl, z_bf, A_log, Dvec, sc_h, y_bf);

    // out_proj (8-phase 256^2, split-K x 2 so 256 blocks fill 256 CUs;
    // z_bf/xconv regions are dead after phase3 -> hold the 64 MiB partials)
    gemm_256<0,0,1><<<dim3(MROWS/256, DMODEL/256, 2), blk5, 0, stream>>>(
        y_bf, DINNER, wo_bf, DINNER, op_par, nullptr, DMODEL, DINNER/2);
    reduce2<<<dim3(MROWS*DMODEL/4/256), blk, 0, stream>>>(op_par, out, MROWS*DMODEL/4);
}

// Round 2
// 669.775 us; speedup vs baseline: 1.0236x; 1.0236x over previous
//
#include <hip/hip_runtime.h>
#include <math.h>

#define B_ 2
#define L_ 2048
#define DMODEL 2048
#define DINNER 4096
#define DSTATE 16
#define DCONV 4
#define DTRANK 128
#define NCHUNK 32
#define CLEN 64           // L_/NCHUNK
#define MROWS 4096        // B_*L_

typedef unsigned short ushort_t;
typedef unsigned int uint_t;
typedef __attribute__((ext_vector_type(8))) short bf16x8;
typedef __attribute__((ext_vector_type(4))) float floatx4;

__device__ __forceinline__ float sigmoidf_(float x){ return 1.f/(1.f+__expf(-x)); }
__device__ __forceinline__ ushort_t f2bf(float f){
    uint_t u = __builtin_bit_cast(uint_t, f);
    return (ushort_t)((u + 0x7FFFu + ((u >> 16) & 1u)) >> 16);
}
__device__ __forceinline__ float bf2f(ushort_t h){
    return __builtin_bit_cast(float, (uint_t)h << 16);
}
__device__ __forceinline__ float fast_exp2(float x){
#if __has_builtin(__builtin_amdgcn_exp2f)
    return __builtin_amdgcn_exp2f(x);
#else
    return exp2f(x);
#endif
}
#define LOG2E 1.44269504088896f

#define GLD_LDS16(g, l) __builtin_amdgcn_global_load_lds( \
    (const __attribute__((address_space(1))) void*)(g),   \
    (__attribute__((address_space(3))) void*)(l), 16, 0, 0)

// ---------------------------------------------------------------------------
// 128x128 bf16 MFMA GEMM (m97 structure) — used for x_proj (split-K, N=256),
// dt_proj (K=128), out_proj (N=2048 -> 512 blocks fill the machine).
// ---------------------------------------------------------------------------
template<int OUTBF, int EPI, int SPLIT, int KSPLIT>
__global__ __launch_bounds__(256)
void gemm_mfma(const ushort_t* __restrict__ Aptr, int lda,
               const ushort_t* __restrict__ W, int ldw,
               void* __restrict__ Cptr, void* __restrict__ C2,
               int ldc, int Klen,
               const float* __restrict__ bias)
{
    __shared__ ushort_t lsA[128*64];
    __shared__ ushort_t lsW[128*64];
    const int tid  = threadIdx.x;
    const int row0 = blockIdx.x * 128;
    const int col0 = blockIdx.y * 128;
    const int koff = KSPLIT ? blockIdx.z * Klen : 0;
    const int lane = tid & 63;
    const int wv   = tid >> 6;
    const int wm   = (wv >> 1) * 64;
    const int wn   = (wv & 1) * 64;
    const int lr   = lane & 15;
    const int lq   = lane >> 4;

    floatx4 acc[4][4];
    #pragma unroll
    for(int i=0;i<4;i++)
        #pragma unroll
        for(int j=0;j<4;j++)
            #pragma unroll
            for(int r=0;r<4;r++) acc[i][j][r] = 0.f;

    for(int k0 = koff; k0 < koff + Klen; k0 += 64){
        #pragma unroll
        for(int it=0; it<4; it++){
            const int slot = it*256 + tid;
            const int row  = slot >> 3;
            const int p    = slot & 7;
            const int s    = p ^ (row & 7);
            const ushort_t* gw = W    + (size_t)(col0 + row)*ldw + k0 + s*8;
            const ushort_t* ga = Aptr + (size_t)(row0 + row)*lda + k0 + s*8;
            GLD_LDS16(gw, &lsW[slot*8]);
            GLD_LDS16(ga, &lsA[slot*8]);
        }
        __syncthreads();

        #pragma unroll
        for(int kk=0; kk<2; kk++){
            bf16x8 af[4], bw[4];
            #pragma unroll
            for(int i=0;i<4;i++){
                const int ra = wm + i*16 + lr;
                const int rb = wn + i*16 + lr;
                af[i] = *(const bf16x8*)&lsA[ra*64 + (((kk*4+lq) ^ (ra&7))*8)];
                bw[i] = *(const bf16x8*)&lsW[rb*64 + (((kk*4+lq) ^ (rb&7))*8)];
            }
            #pragma unroll
            for(int i=0;i<4;i++)
                #pragma unroll
                for(int j=0;j<4;j++)
                    acc[i][j] = __builtin_amdgcn_mfma_f32_16x16x32_bf16(af[i], bw[j], acc[i][j], 0, 0, 0);
        }
        __syncthreads();
    }

    void* dst = Cptr;
    int cbase = col0;
    if (SPLIT && col0 >= ldc){ dst = C2; cbase = col0 - ldc; }
    const size_t zoff = KSPLIT ? (size_t)blockIdx.z * MROWS * ldc : 0;

    #pragma unroll
    for(int i=0;i<4;i++){
        #pragma unroll
        for(int r=0;r<4;r++){
            const int row = row0 + wm + i*16 + lq*4 + r;
            #pragma unroll
            for(int j=0;j<4;j++){
                const int col = cbase + wn + j*16 + lr;
                float v = acc[i][j][r];
                if (EPI){
                    v += bias[col];
                    v = (v > 20.f) ? v : log1pf(expf(v));
                }
                if (OUTBF) ((ushort_t*)dst)[(size_t)row*ldc + col] = f2bf(v);
                else       ((float*)  dst)[zoff + (size_t)row*ldc + col] = v;
            }
        }
    }
}

// ---------------------------------------------------------------------------
// 256x256 bf16 GEMM v2: C[M,N]=A[M,K]*W[N,K]^T. 512 thr = 8 waves (2M x 4N),
// per-wave output 128x64, BK=64 (2 K-halves). LDS 128 KiB =
// [dbuf][A/W][khalf][256x32].
// v2 schedule: 2 coarse phases per K-tile (one per K-half):
//   { 12 ds_read_b128 (b[4]+af[8]) ; 2 STG pairs ; setprio(1) ; 32 MFMA ;
//     setprio(0) ; counted vmcnt + s_barrier }
// Only these 2 barriers per K-tile are needed: all intra-tile reads come from
// buffer c while all STGs target c^1 (or the already-consumed kh0 of c).
// No inline lgkm waits: the compiler emits counted lgkmcnt from dataflow, so
// MFMA(i0-3) issues while af[4..7] reads are in flight, and the next phase's
// reads execute while the 32-MFMA backlog drains the matrix pipe.
// vmcnt ladder (4 loads per STG pair, steady state 8-12 in flight):
//   mid-tile:  need A1(t),W1(t)   -> newer = 8 (tail: 0)
//   end-tile:  need A0(t+1),W0(t+1) -> newer = 8 (tail: 4 / skip)
// Swizzle (unchanged, 0 conflicts measured): chunk f of double-row dr holds
// (row 2dr+b, K-seg s), b*4+s = f^(dr&7); linear gload_lds dest, pre-swizzled
// per-lane source; ds_read slot f = ((lr&1)*4+lq)^(lr>>1). NT >= 2 required.
// ---------------------------------------------------------------------------
template<int OUTBF, int SPLIT, int KSPLIT>
__global__ __launch_bounds__(512, 2)
void gemm_256(const ushort_t* __restrict__ Aptr, int lda,
              const ushort_t* __restrict__ W, int ldw,
              void* __restrict__ Cptr, void* __restrict__ C2,
              int ldc, int Klen)
{
    __shared__ ushort_t lds[2][2][2][8192];   // [dbuf][A/W][khalf][256x32]
    const int tid  = threadIdx.x;
    const int row0 = blockIdx.x * 256;
    const int col0 = blockIdx.y * 256;
    const int koff = KSPLIT ? blockIdx.z * Klen : 0;
    const int NT   = Klen >> 6;
    const int lane = tid & 63;
    const int wv   = tid >> 6;
    const int wr   = wv >> 2;          // 0..1 : M half (128 rows)
    const int wc   = wv & 3;           // 0..3 : N quarter (64 cols)
    const int lr   = lane & 15;
    const int lq   = lane >> 4;

    // staging: chunk g = it*512+tid in [0,1024): dr=g>>3, f=g&7, u=f^(dr&7)
    // -> source row 2*dr+(u>>2), source K-seg (u&3)*8; LDS dest linear g*8.
    int sdst0, sdst1;
    const ushort_t *aS0, *aS1, *wS0, *wS1;
    {
        const int g0 = tid,     dr0 = g0 >> 3, f0 = g0 & 7;
        const int g1 = 512+tid, dr1 = g1 >> 3, f1 = g1 & 7;
        const int u0 = f0 ^ (dr0 & 7), u1 = f1 ^ (dr1 & 7);
        const int r0s = dr0*2 + (u0 >> 2), c0s = (u0 & 3)*8;
        const int r1s = dr1*2 + (u1 >> 2), c1s = (u1 & 3)*8;
        sdst0 = g0*8; sdst1 = g1*8;
        aS0 = Aptr + (size_t)(row0 + r0s)*lda + c0s;
        aS1 = Aptr + (size_t)(row0 + r1s)*lda + c1s;
        wS0 = W    + (size_t)(col0 + r0s)*ldw + c0s;
        wS1 = W    + (size_t)(col0 + r1s)*ldw + c1s;
    }
    #define STG_A(kc, reg) { GLD_LDS16(aS0 + (kc), &(reg)[sdst0]); \
                             GLD_LDS16(aS1 + (kc), &(reg)[sdst1]); }
    #define STG_W(kc, reg) { GLD_LDS16(wS0 + (kc), &(reg)[sdst0]); \
                             GLD_LDS16(wS1 + (kc), &(reg)[sdst1]); }

    // ds_read base (ushort units): fragment i at base + i*512
    const int frd = ((lr & 1)*4 + lq) ^ (lr >> 1);
    const int aA  = (wr*64 + (lr >> 1))*64 + frd*8;
    const int aB  = (wc*32 + (lr >> 1))*64 + frd*8;

    floatx4 acc[8][4];
    #pragma unroll
    for(int i=0;i<8;i++)
        #pragma unroll
        for(int j=0;j<4;j++)
            #pragma unroll
            for(int r=0;r<4;r++) acc[i][j][r] = 0.f;

    // prologue: A0(0) W0(0) A1(0) W1(0) A0(1) W0(1) = 12 loads;
    // wait oldest 4 (Kh0 of tile 0) -> 8 in flight.
    STG_A(koff,    lds[0][0][0]);
    STG_W(koff,    lds[0][1][0]);
    STG_A(koff+32, lds[0][0][1]);
    STG_W(koff+32, lds[0][1][1]);
    STG_A(koff+64, lds[1][0][0]);
    STG_W(koff+64, lds[1][1][0]);
    asm volatile("s_waitcnt vmcnt(8)\ns_barrier" ::: "memory");

    for(int t=0; t<NT; ++t){
        const int c = t & 1;
        const ushort_t* cA0 = lds[c][0][0];
        const ushort_t* cB0 = lds[c][1][0];
        const ushort_t* cA1 = lds[c][0][1];
        const ushort_t* cB1 = lds[c][1][1];
        const int kt1 = koff + (t+1)*64;
        const int kt2 = koff + (t+2)*64;
        bf16x8 bw[4], af[8];

        // ======== phase alpha: K-half 0 ========
        #pragma unroll
        for(int j=0;j<4;j++) bw[j] = *(const bf16x8*)&cB0[aB + j*512];
        #pragma unroll
        for(int i=0;i<8;i++) af[i] = *(const bf16x8*)&cA0[aA + i*512];
        if (t+1 < NT){
            STG_A(kt1+32, lds[c^1][0][1]);      // A1(t+1)
            STG_W(kt1+32, lds[c^1][1][1]);      // W1(t+1)
        }
        __builtin_amdgcn_s_setprio(1);
        #pragma unroll
        for(int i=0;i<8;i++)
            #pragma unroll
            for(int j=0;j<4;j++)
                acc[i][j] = __builtin_amdgcn_mfma_f32_16x16x32_bf16(af[i], bw[j], acc[i][j],0,0,0);
        __builtin_amdgcn_s_setprio(0);
        if (t+1 < NT) asm volatile("s_waitcnt vmcnt(8)\ns_barrier" ::: "memory");
        else          asm volatile("s_waitcnt vmcnt(0)\ns_barrier" ::: "memory");

        // ======== phase beta: K-half 1 ========
        #pragma unroll
        for(int j=0;j<4;j++) bw[j] = *(const bf16x8*)&cB1[aB + j*512];
        #pragma unroll
        for(int i=0;i<8;i++) af[i] = *(const bf16x8*)&cA1[aA + i*512];
        if (t+2 < NT){
            STG_A(kt2, lds[c][0][0]);           // A0(t+2) -> kh0 of c (already consumed)
            STG_W(kt2, lds[c][1][0]);           // W0(t+2)
        }
        __builtin_amdgcn_s_setprio(1);
        #pragma unroll
        for(int i=0;i<8;i++)
            #pragma unroll
            for(int j=0;j<4;j++)
                acc[i][j] = __builtin_amdgcn_mfma_f32_16x16x32_bf16(af[i], bw[j], acc[i][j],0,0,0);
        __builtin_amdgcn_s_setprio(0);
        if (t+2 < NT)      asm volatile("s_waitcnt vmcnt(8)\ns_barrier" ::: "memory");
        else if (t+1 < NT) asm volatile("s_waitcnt vmcnt(4)\ns_barrier" ::: "memory");
        // last tile: no further LDS reads, no barrier needed
    }
    #undef STG_A
    #undef STG_W

    void* dst = Cptr;
    int cb = col0;
    if (SPLIT && col0 >= ldc){ dst = C2; cb = col0 - ldc; }
    const size_t zoff = KSPLIT ? (size_t)blockIdx.z * MROWS * ldc : 0;
    const int rbase = row0 + wr*128 + lq*4;
    const int cbase = cb + wc*64 + lr;
    #pragma unroll
    for(int i=0;i<8;i++){
        #pragma unroll
        for(int r=0;r<4;r++){
            const int row = rbase + i*16 + r;
            #pragma unroll
            for(int j=0;j<4;j++){
                const int col = cbase + j*16;
                const float v = acc[i][j][r];
                if (OUTBF) ((ushort_t*)dst)[(size_t)row*ldc + col] = f2bf(v);
                else       ((float*)dst)[zoff + (size_t)row*ldc + col] = v;
            }
        }
    }
}

// f32 -> bf16 cast, 4 elems/thread
__global__ __launch_bounds__(256)
void cvt_bf16(const float* __restrict__ in, ushort_t* __restrict__ out, int n4)
{
    const int i = blockIdx.x*256 + threadIdx.x;
    if (i < n4){
        float4 v = *(const float4*)(in + (size_t)i*4);
        union { ushort_t u[4]; uint2 q; } p;
        p.u[0]=f2bf(v.x); p.u[1]=f2bf(v.y); p.u[2]=f2bf(v.z); p.u[3]=f2bf(v.w);
        *(uint2*)(out + (size_t)i*4) = p.q;
    }
}

// w_xproj 160x4096 f32 -> 256x4096 bf16, rows 160..255 zero
__global__ __launch_bounds__(256)
void cvt_pad256(const float* __restrict__ in, ushort_t* __restrict__ out)
{
    const int i = blockIdx.x*256 + threadIdx.x;
    const int row = i >> 10;
    const int c4  = i & 1023;
    union { ushort_t u[4]; uint2 q; } p;
    if (row < 160){
        float4 v = *(const float4*)(in + (size_t)row*4096 + c4*4);
        p.u[0]=f2bf(v.x); p.u[1]=f2bf(v.y); p.u[2]=f2bf(v.z); p.u[3]=f2bf(v.w);
    } else { p.u[0]=0; p.u[1]=0; p.u[2]=0; p.u[3]=0; }
    *(uint2*)(out + (size_t)i*4) = p.q;
}

// reduce split-K partials P[8][4096][256] -> xdbl f32 (ld 160) + dtlo bf16 (ld 128)
__global__ __launch_bounds__(256)
void reduce_xproj(const float* __restrict__ P, float* __restrict__ xdbl,
                  ushort_t* __restrict__ dtlo)
{
    const int row = blockIdx.x;
    const int col = threadIdx.x;
    float s = 0.f;
    #pragma unroll
    for(int z=0; z<8; z++)
        s += P[(size_t)z*MROWS*256 + (size_t)row*256 + col];
    if (col < 160) xdbl[(size_t)row*160 + col] = s;
    if (col < DTRANK) dtlo[(size_t)row*DTRANK + col] = f2bf(s);
}

// depthwise causal conv (k=4) + bias + silu, bf16 in/out
__global__ __launch_bounds__(256)
void conv_silu_bf(const ushort_t* __restrict__ xb, const float* __restrict__ w,
                  const float* __restrict__ bias, ushort_t* __restrict__ xc)
{
    const int gid = blockIdx.x*256 + threadIdx.x;
    const int d = gid & (DINNER-1);
    const int t = gid >> 12;
    const int l = t & (L_-1);
    float s = bias[d];
    #pragma unroll
    for(int j=0;j<DCONV;j++){
        const int ll = l - (DCONV-1) + j;
        if (ll >= 0)
            s = fmaf(bf2f(xb[(size_t)(t-(DCONV-1)+j)*DINNER + d]), w[d*DCONV+j], s);
    }
    xc[(size_t)t*DINNER + d] = f2bf(s * sigmoidf_(s));
}

// ---- chunked scan, one thread per channel d, 16 states in registers ----
__global__ __launch_bounds__(256)
void scan_phase1(const ushort_t* __restrict__ dt_bf,
                 const ushort_t* __restrict__ xconv,
                 const float* __restrict__ xdbl,
                 const float* __restrict__ A_log,
                 float* __restrict__ sc_h, float* __restrict__ sc_S)
{
    const int tid = threadIdx.x;
    const int d = blockIdx.x*256 + tid;
    const int chunk = blockIdx.y;
    const int b = blockIdx.z;
    const int l0 = chunk*CLEN;

    __shared__ float Bs[CLEN][DSTATE];
    for(int i=tid; i<CLEN*DSTATE; i+=256){
        const int row = i >> 4, n = i & 15;
        Bs[row][n] = xdbl[(size_t)(b*L_ + l0 + row)*160 + DTRANK + n];
    }
    float negA[DSTATE];
    #pragma unroll
    for(int n=0;n<DSTATE;n++) negA[n] = -expf(A_log[d*DSTATE + n]) * LOG2E;
    __syncthreads();

    float h[DSTATE], S[DSTATE];
    #pragma unroll
    for(int n=0;n<DSTATE;n++){ h[n]=0.f; S[n]=0.f; }

    size_t idx = (size_t)(b*L_ + l0)*DINNER + d;
    float dt_c = bf2f(dt_bf[idx]);
    float xv_c = bf2f(xconv[idx]);
    for(int l=0;l<CLEN;l++){
        float dt_n = 0.f, xv_n = 0.f;
        if (l+1 < CLEN){
            dt_n = bf2f(dt_bf[idx + DINNER]);
            xv_n = bf2f(xconv[idx + DINNER]);
        }
        const float dx = dt_c * xv_c;
        #pragma unroll
        for(int n=0;n<DSTATE;n++){
            const float t = dt_c * negA[n];
            S[n] += t;
            h[n] = fmaf(h[n], fast_exp2(t), dx*Bs[l][n]);
        }
        dt_c = dt_n; xv_c = xv_n;
        idx += DINNER;
    }
    const size_t o = (size_t)(b*NCHUNK + chunk)*DSTATE*DINNER + d;
    #pragma unroll
    for(int n=0;n<DSTATE;n++){
        sc_h[o + (size_t)n*DINNER] = h[n];
        sc_S[o + (size_t)n*DINNER] = S[n];
    }
}

__global__ __launch_bounds__(256)
void scan_phase2(float* __restrict__ sc_h, const float* __restrict__ sc_S)
{
    const int gid = blockIdx.x*256 + threadIdx.x;
    const int b = gid / (DSTATE*DINNER);
    const int rem = gid - b*DSTATE*DINNER;
    const size_t base = (size_t)b*NCHUNK*DSTATE*DINNER + rem;
    float H = 0.f;
    #pragma unroll
    for(int c=0;c<NCHUNK;c++){
        const size_t idx = base + (size_t)c*DSTATE*DINNER;
        const float he = sc_h[idx];
        const float S  = sc_S[idx];
        sc_h[idx] = H;
        H = fmaf(fast_exp2(S), H, he);
    }
}

__global__ __launch_bounds__(256)
void scan_phase3(const ushort_t* __restrict__ dt_bf,
                 const ushort_t* __restrict__ xconv,
                 const float* __restrict__ xdbl,
                 const ushort_t* __restrict__ z_bf,
                 const float* __restrict__ A_log,
                 const float* __restrict__ Dvec,
                 const float* __restrict__ sc_h,
                 ushort_t* __restrict__ y_bf)
{
    const int tid = threadIdx.x;
    const int d = blockIdx.x*256 + tid;
    const int chunk = blockIdx.y;
    const int b = blockIdx.z;
    const int l0 = chunk*CLEN;

    __shared__ float BCs[CLEN][2*DSTATE];
    for(int i=tid; i<CLEN*2*DSTATE; i+=256){
        const int row = i >> 5, c = i & 31;
        BCs[row][c] = xdbl[(size_t)(b*L_ + l0 + row)*160 + DTRANK + c];
    }
    float negA[DSTATE];
    #pragma unroll
    for(int n=0;n<DSTATE;n++) negA[n] = -expf(A_log[d*DSTATE + n]) * LOG2E;
    const float Dv = Dvec[d];
    float h[DSTATE];
    const size_t o = (size_t)(b*NCHUNK + chunk)*DSTATE*DINNER + d;
    #pragma unroll
    for(int n=0;n<DSTATE;n++) h[n] = sc_h[o + (size_t)n*DINNER];
    __syncthreads();

    size_t idx = (size_t)(b*L_ + l0)*DINNER + d;
    float dt_c = bf2f(dt_bf[idx]);
    float xv_c = bf2f(xconv[idx]);
    float zv_c = bf2f(z_bf[idx]);
    for(int l=0;l<CLEN;l++){
        float dt_n = 0.f, xv_n = 0.f, zv_n = 0.f;
        if (l+1 < CLEN){
            dt_n = bf2f(dt_bf[idx + DINNER]);
            xv_n = bf2f(xconv[idx + DINNER]);
            zv_n = bf2f(z_bf[idx + DINNER]);
        }
        const float dx = dt_c * xv_c;
        float y = 0.f;
        #pragma unroll
        for(int n=0;n<DSTATE;n++){
            const float t = dt_c * negA[n];
            h[n] = fmaf(h[n], fast_exp2(t), dx*BCs[l][n]);
            y = fmaf(h[n], BCs[l][DSTATE+n], y);
        }
        const float g = zv_c * sigmoidf_(zv_c);
        y_bf[idx] = f2bf(fmaf(xv_c, Dv, y) * g);
        dt_c = dt_n; xv_c = xv_n; zv_c = zv_n;
        idx += DINNER;
    }
}

extern "C" void kernel_launch(void* const* d_in, const int* in_sizes, int n_in,
                              void* d_out, int out_size, void* d_ws, size_t ws_size,
                              hipStream_t stream) {
    const float* hs      = (const float*)d_in[0];
    const float* w_in    = (const float*)d_in[1];
    const float* w_conv  = (const float*)d_in[2];
    const float* b_conv  = (const float*)d_in[3];
    const float* w_xproj = (const float*)d_in[4];
    const float* w_dt    = (const float*)d_in[5];
    const float* b_dt    = (const float*)d_in[6];
    const float* w_out   = (const float*)d_in[7];
    const float* A_log   = (const float*)d_in[8];
    const float* Dvec    = (const float*)d_in[9];
    float* out = (float*)d_out;

    // workspace layout (peak 176 MiB):
    // [0,32M)    x_bf -> after conv: xdbl@0, wx_bf@4M, dtlo@6M, wdt@7M, sc_h@8M(16M)
    // [32M,64M)  z_bf               (live to phase3)
    // [64M,96M)  xconv              (live to phase3)
    // [96M,128M) wi_bf -> after in_proj: dt_bf
    // [128M,144M) hs_bf -> after in_proj: sc_S -> after phase2: wo_bf
    // [144M,176M) y_bf  (also x_proj split-K partials, dead before phase3)
    char* base = (char*)d_ws;
    ushort_t* x_bf   = (ushort_t*)(base);
    float*    xdbl   = (float*)   (base);
    ushort_t* wx_bf  = (ushort_t*)(base + (4u<<20));
    ushort_t* dtlo_bf= (ushort_t*)(base + (6u<<20));
    ushort_t* wdt_bf = (ushort_t*)(base + (7u<<20));
    float*    sc_h   = (float*)   (base + (8u<<20));
    ushort_t* z_bf   = (ushort_t*)(base + (32u<<20));
    ushort_t* xconv  = (ushort_t*)(base + (64u<<20));
    ushort_t* wi_bf  = (ushort_t*)(base + (96u<<20));
    ushort_t* dt_bf  = (ushort_t*)(base + (96u<<20));
    ushort_t* hs_bf  = (ushort_t*)(base + (128u<<20));
    float*    sc_S   = (float*)   (base + (128u<<20));
    ushort_t* wo_bf  = (ushort_t*)(base + (128u<<20));
    float*    xp_par = (float*)   (base + (144u<<20));  // 8*4096*256*4 = 32 MiB
    ushort_t* y_bf   = (ushort_t*)(base + (144u<<20));

    dim3 blk(256);
    dim3 blk5(512);

    // convert activations + in_proj weights to bf16
    cvt_bf16<<<dim3(MROWS*DMODEL/4/256), blk, 0, stream>>>(hs, hs_bf, MROWS*DMODEL/4);
    cvt_bf16<<<dim3(2*DINNER*DMODEL/4/256), blk, 0, stream>>>(w_in, wi_bf, 2*DINNER*DMODEL/4);

    // fused in_proj (256^2 v2 schedule): N=8192, split-store x half / z half
    gemm_256<1,1,0><<<dim3(MROWS/256, 2*DINNER/256), blk5, 0, stream>>>(
        hs_bf, DMODEL, wi_bf, DMODEL, x_bf, z_bf, DINNER, DMODEL);

    // conv + silu -> xconv bf16 (x_bf region becomes free after this)
    conv_silu_bf<<<dim3((size_t)MROWS*DINNER/256), blk, 0, stream>>>(x_bf, w_conv, b_conv, xconv);

    // x_proj: split-K x 8 into f32 partials, then reduce (+fused dtlo cvt)
    cvt_pad256<<<dim3(256*4096/4/256), blk, 0, stream>>>(w_xproj, wx_bf);
    gemm_mfma<0,0,0,1><<<dim3(MROWS/128, 2, 8), blk, 0, stream>>>(
        xconv, DINNER, wx_bf, DINNER, xp_par, nullptr, 256, DINNER/8, nullptr);
    reduce_xproj<<<dim3(MROWS), blk, 0, stream>>>(xp_par, xdbl, dtlo_bf);

    // dt_proj + bias + softplus -> dt_bf (overwrites dead wi_bf region)
    cvt_bf16<<<dim3(DINNER*DTRANK/4/256), blk, 0, stream>>>(w_dt, wdt_bf, DINNER*DTRANK/4);
    gemm_mfma<1,1,0,0><<<dim3(MROWS/128, DINNER/128), blk, 0, stream>>>(
        dtlo_bf, DTRANK, wdt_bf, DTRANK, dt_bf, nullptr, DINNER, DTRANK, b_dt);

    // chunked selective scan (thread-per-channel, coalesced)
    dim3 sgrid(DINNER/256, NCHUNK, B_);
    scan_phase1<<<sgrid, blk, 0, stream>>>(dt_bf, xconv, xdbl, A_log, sc_h, sc_S);
    scan_phase2<<<dim3(B_*DSTATE*DINNER/256), blk, 0, stream>>>(sc_h, sc_S);

    // w_out conversion (sc_S dead after phase2; reuse its region)
    cvt_bf16<<<dim3(DMODEL*DINNER/4/256), blk, 0, stream>>>(w_out, wo_bf, DMODEL*DINNER/4);

    scan_phase3<<<sgrid, blk, 0, stream>>>(dt_bf, xconv, xdbl, z_bf, A_log, Dvec, sc_h, y_bf);

    // out_proj (128^2 kernel, 512 blocks -> full machine, direct f32 out)
    gemm_mfma<0,0,0,0><<<dim3(MROWS/128, DMODEL/128), blk, 0, stream>>>(
        y_bf, DINNER, wo_bf, DINNER, out, nullptr, DMODEL, DINNER, nullptr);
}

// Round 3
// 658.871 us; speedup vs baseline: 1.0406x; 1.0165x over previous
//
#include <hip/hip_runtime.h>
#include <math.h>

#define B_ 2
#define L_ 2048
#define DMODEL 2048
#define DINNER 4096
#define DSTATE 16
#define DCONV 4
#define DTRANK 128
#define NCHUNK 32
#define CLEN 64           // L_/NCHUNK
#define MROWS 4096        // B_*L_

typedef unsigned short ushort_t;
typedef unsigned int uint_t;
typedef __attribute__((ext_vector_type(8))) short bf16x8;
typedef __attribute__((ext_vector_type(4))) float floatx4;

__device__ __forceinline__ float sigmoidf_(float x){ return 1.f/(1.f+__expf(-x)); }
__device__ __forceinline__ ushort_t f2bf(float f){
    uint_t u = __builtin_bit_cast(uint_t, f);
    return (ushort_t)((u + 0x7FFFu + ((u >> 16) & 1u)) >> 16);
}
__device__ __forceinline__ float bf2f(ushort_t h){
    return __builtin_bit_cast(float, (uint_t)h << 16);
}
__device__ __forceinline__ float fast_exp2(float x){
#if __has_builtin(__builtin_amdgcn_exp2f)
    return __builtin_amdgcn_exp2f(x);
#else
    return exp2f(x);
#endif
}
#define LOG2E 1.44269504088896f

#define GLD_LDS16(g, l) __builtin_amdgcn_global_load_lds( \
    (const __attribute__((address_space(1))) void*)(g),   \
    (__attribute__((address_space(3))) void*)(l), 16, 0, 0)

// ---------------------------------------------------------------------------
// 128x128 bf16 MFMA GEMM (m97 structure) — used for x_proj (split-K, N=256),
// dt_proj (K=128), out_proj (N=2048 -> 512 blocks fill the machine).
// ---------------------------------------------------------------------------
template<int OUTBF, int EPI, int SPLIT, int KSPLIT>
__global__ __launch_bounds__(256)
void gemm_mfma(const ushort_t* __restrict__ Aptr, int lda,
               const ushort_t* __restrict__ W, int ldw,
               void* __restrict__ Cptr, void* __restrict__ C2,
               int ldc, int Klen,
               const float* __restrict__ bias)
{
    __shared__ ushort_t lsA[128*64];
    __shared__ ushort_t lsW[128*64];
    const int tid  = threadIdx.x;
    const int row0 = blockIdx.x * 128;
    const int col0 = blockIdx.y * 128;
    const int koff = KSPLIT ? blockIdx.z * Klen : 0;
    const int lane = tid & 63;
    const int wv   = tid >> 6;
    const int wm   = (wv >> 1) * 64;
    const int wn   = (wv & 1) * 64;
    const int lr   = lane & 15;
    const int lq   = lane >> 4;

    floatx4 acc[4][4];
    #pragma unroll
    for(int i=0;i<4;i++)
        #pragma unroll
        for(int j=0;j<4;j++)
            #pragma unroll
            for(int r=0;r<4;r++) acc[i][j][r] = 0.f;

    for(int k0 = koff; k0 < koff + Klen; k0 += 64){
        #pragma unroll
        for(int it=0; it<4; it++){
            const int slot = it*256 + tid;
            const int row  = slot >> 3;
            const int p    = slot & 7;
            const int s    = p ^ (row & 7);
            const ushort_t* gw = W    + (size_t)(col0 + row)*ldw + k0 + s*8;
            const ushort_t* ga = Aptr + (size_t)(row0 + row)*lda + k0 + s*8;
            GLD_LDS16(gw, &lsW[slot*8]);
            GLD_LDS16(ga, &lsA[slot*8]);
        }
        __syncthreads();

        #pragma unroll
        for(int kk=0; kk<2; kk++){
            bf16x8 af[4], bw[4];
            #pragma unroll
            for(int i=0;i<4;i++){
                const int ra = wm + i*16 + lr;
                const int rb = wn + i*16 + lr;
                af[i] = *(const bf16x8*)&lsA[ra*64 + (((kk*4+lq) ^ (ra&7))*8)];
                bw[i] = *(const bf16x8*)&lsW[rb*64 + (((kk*4+lq) ^ (rb&7))*8)];
            }
            #pragma unroll
            for(int i=0;i<4;i++)
                #pragma unroll
                for(int j=0;j<4;j++)
                    acc[i][j] = __builtin_amdgcn_mfma_f32_16x16x32_bf16(af[i], bw[j], acc[i][j], 0, 0, 0);
        }
        __syncthreads();
    }

    void* dst = Cptr;
    int cbase = col0;
    if (SPLIT && col0 >= ldc){ dst = C2; cbase = col0 - ldc; }
    const size_t zoff = KSPLIT ? (size_t)blockIdx.z * MROWS * ldc : 0;

    #pragma unroll
    for(int i=0;i<4;i++){
        #pragma unroll
        for(int r=0;r<4;r++){
            const int row = row0 + wm + i*16 + lq*4 + r;
            #pragma unroll
            for(int j=0;j<4;j++){
                const int col = cbase + wn + j*16 + lr;
                float v = acc[i][j][r];
                if (EPI){
                    v += bias[col];
                    v = (v > 20.f) ? v : log1pf(expf(v));
                }
                if (OUTBF) ((ushort_t*)dst)[(size_t)row*ldc + col] = f2bf(v);
                else       ((float*)  dst)[zoff + (size_t)row*ldc + col] = v;
            }
        }
    }
}

// ---------------------------------------------------------------------------
// 256x256 bf16 GEMM v3: C[M,N]=A[M,K]*W[N,K]^T. 512 thr = 8 waves (2M x 4N),
// per-wave output 128x64, BK=64. LDS 128 KiB = [buf][A/W][khalf][256x32].
// v3 schedule — full-tile double-buffer + wave-group anti-phase:
//   per K-tile u (c=u&1):
//     s_waitcnt vmcnt(0); s_barrier;          // tile u landed (issued @u-1)
//     STG tile u+1 -> buf c^1 (8 gload_lds);  // only VM ops in loop
//     waves 0-3: compute kh0 then kh1; waves 4-7: kh1 then kh0.
//   Waves 0-3 and 4-7 sit on the same SIMDs pairwise (wv, wv+4), so at any
//   instant ~one wave per SIMD is in its MFMA block (setprio(1)) while the
//   other drains the CU-shared LDS pipe -> LDS reads (~1536-2300 cyc/tile)
//   hide under MFMA (~2068 cyc/tile) instead of serializing with it.
//   vmcnt(0) waits loads issued one full tile (~2000 cyc) earlier => free.
//   WAR safety: buf c^1 overwritten at top of u was last read in body u-1;
//   each wave's reads were drained by its MFMA operand lgkm-waits before it
//   reached the tile-u barrier. One barrier per K-tile total.
// Swizzle (unchanged, 0 conflicts measured): chunk f of double-row dr holds
// (row 2dr+b, K-seg s), b*4+s = f^(dr&7); linear gload_lds dest, pre-swizzled
// per-lane source; ds_read slot f = ((lr&1)*4+lq)^(lr>>1).
// ---------------------------------------------------------------------------
template<int OUTBF, int SPLIT, int KSPLIT>
__global__ __launch_bounds__(512, 2)
void gemm_256(const ushort_t* __restrict__ Aptr, int lda,
              const ushort_t* __restrict__ W, int ldw,
              void* __restrict__ Cptr, void* __restrict__ C2,
              int ldc, int Klen)
{
    __shared__ ushort_t lds[2][2][2][8192];   // [buf][A/W][khalf][256x32]
    const int tid  = threadIdx.x;
    const int row0 = blockIdx.x * 256;
    const int col0 = blockIdx.y * 256;
    const int koff = KSPLIT ? blockIdx.z * Klen : 0;
    const int NT   = Klen >> 6;
    const int lane = tid & 63;
    const int wv   = tid >> 6;
    const int wr   = wv >> 2;          // 0..1 : M half (128 rows) == wave group
    const int wc   = wv & 3;           // 0..3 : N quarter (64 cols)
    const int lr   = lane & 15;
    const int lq   = lane >> 4;

    // staging: chunk g = it*512+tid in [0,1024): dr=g>>3, f=g&7, u=f^(dr&7)
    // -> source row 2*dr+(u>>2), source K-seg (u&3)*8; LDS dest linear g*8.
    int sdst0, sdst1;
    const ushort_t *aS0, *aS1, *wS0, *wS1;
    {
        const int g0 = tid,     dr0 = g0 >> 3, f0 = g0 & 7;
        const int g1 = 512+tid, dr1 = g1 >> 3, f1 = g1 & 7;
        const int u0 = f0 ^ (dr0 & 7), u1 = f1 ^ (dr1 & 7);
        const int r0s = dr0*2 + (u0 >> 2), c0s = (u0 & 3)*8;
        const int r1s = dr1*2 + (u1 >> 2), c1s = (u1 & 3)*8;
        sdst0 = g0*8; sdst1 = g1*8;
        aS0 = Aptr + (size_t)(row0 + r0s)*lda + c0s;
        aS1 = Aptr + (size_t)(row0 + r1s)*lda + c1s;
        wS0 = W    + (size_t)(col0 + r0s)*ldw + c0s;
        wS1 = W    + (size_t)(col0 + r1s)*ldw + c1s;
    }
    #define STG_A(kc, reg) { GLD_LDS16(aS0 + (kc), &(reg)[sdst0]); \
                             GLD_LDS16(aS1 + (kc), &(reg)[sdst1]); }
    #define STG_W(kc, reg) { GLD_LDS16(wS0 + (kc), &(reg)[sdst0]); \
                             GLD_LDS16(wS1 + (kc), &(reg)[sdst1]); }

    // ds_read base (ushort units): fragment i at base + i*512
    const int frd = ((lr & 1)*4 + lq) ^ (lr >> 1);
    const int aA  = (wr*64 + (lr >> 1))*64 + frd*8;
    const int aB  = (wc*32 + (lr >> 1))*64 + frd*8;

    floatx4 acc[8][4];
    #pragma unroll
    for(int i=0;i<8;i++)
        #pragma unroll
        for(int j=0;j<4;j++)
            #pragma unroll
            for(int r=0;r<4;r++) acc[i][j][r] = 0.f;

    #define HALF_COMPUTE(cbuf, h) { \
        const ushort_t* pA = lds[cbuf][0][h]; \
        const ushort_t* pB = lds[cbuf][1][h]; \
        bf16x8 af[8], bw[4]; \
        _Pragma("unroll") \
        for(int j=0;j<4;j++) bw[j] = *(const bf16x8*)&pB[aB + j*512]; \
        _Pragma("unroll") \
        for(int i=0;i<8;i++) af[i] = *(const bf16x8*)&pA[aA + i*512]; \
        __builtin_amdgcn_s_setprio(1); \
        _Pragma("unroll") \
        for(int i=0;i<8;i++){ \
            _Pragma("unroll") \
            for(int j=0;j<4;j++) \
                acc[i][j] = __builtin_amdgcn_mfma_f32_16x16x32_bf16(af[i], bw[j], acc[i][j],0,0,0); \
        } \
        __builtin_amdgcn_s_setprio(0); }

    // prologue: stage tile 0 into buf 0 (8 loads)
    STG_A(koff,    lds[0][0][0]);
    STG_A(koff+32, lds[0][0][1]);
    STG_W(koff,    lds[0][1][0]);
    STG_W(koff+32, lds[0][1][1]);

    for(int t=0; t<NT; ++t){
        const int c = t & 1;
        asm volatile("s_waitcnt vmcnt(0)\ns_barrier" ::: "memory");
        const int kn = koff + (t+1)*64;
        if (t+1 < NT){
            STG_A(kn,    lds[c^1][0][0]);
            STG_A(kn+32, lds[c^1][0][1]);
            STG_W(kn,    lds[c^1][1][0]);
            STG_W(kn+32, lds[c^1][1][1]);
        }
        if (wr == 0){
            HALF_COMPUTE(c, 0);
            HALF_COMPUTE(c, 1);
        } else {
            HALF_COMPUTE(c, 1);
            HALF_COMPUTE(c, 0);
        }
    }
    #undef HALF_COMPUTE
    #undef STG_A
    #undef STG_W

    void* dst = Cptr;
    int cb = col0;
    if (SPLIT && col0 >= ldc){ dst = C2; cb = col0 - ldc; }
    const size_t zoff = KSPLIT ? (size_t)blockIdx.z * MROWS * ldc : 0;
    const int rbase = row0 + wr*128 + lq*4;
    const int cbase = cb + wc*64 + lr;
    #pragma unroll
    for(int i=0;i<8;i++){
        #pragma unroll
        for(int r=0;r<4;r++){
            const int row = rbase + i*16 + r;
            #pragma unroll
            for(int j=0;j<4;j++){
                const int col = cbase + j*16;
                const float v = acc[i][j][r];
                if (OUTBF) ((ushort_t*)dst)[(size_t)row*ldc + col] = f2bf(v);
                else       ((float*)dst)[zoff + (size_t)row*ldc + col] = v;
            }
        }
    }
}

// f32 -> bf16 cast, 4 elems/thread
__global__ __launch_bounds__(256)
void cvt_bf16(const float* __restrict__ in, ushort_t* __restrict__ out, int n4)
{
    const int i = blockIdx.x*256 + threadIdx.x;
    if (i < n4){
        float4 v = *(const float4*)(in + (size_t)i*4);
        union { ushort_t u[4]; uint2 q; } p;
        p.u[0]=f2bf(v.x); p.u[1]=f2bf(v.y); p.u[2]=f2bf(v.z); p.u[3]=f2bf(v.w);
        *(uint2*)(out + (size_t)i*4) = p.q;
    }
}

// w_xproj 160x4096 f32 -> 256x4096 bf16, rows 160..255 zero
__global__ __launch_bounds__(256)
void cvt_pad256(const float* __restrict__ in, ushort_t* __restrict__ out)
{
    const int i = blockIdx.x*256 + threadIdx.x;
    const int row = i >> 10;
    const int c4  = i & 1023;
    union { ushort_t u[4]; uint2 q; } p;
    if (row < 160){
        float4 v = *(const float4*)(in + (size_t)row*4096 + c4*4);
        p.u[0]=f2bf(v.x); p.u[1]=f2bf(v.y); p.u[2]=f2bf(v.z); p.u[3]=f2bf(v.w);
    } else { p.u[0]=0; p.u[1]=0; p.u[2]=0; p.u[3]=0; }
    *(uint2*)(out + (size_t)i*4) = p.q;
}

// reduce split-K partials P[8][4096][256] -> xdbl f32 (ld 160) + dtlo bf16 (ld 128)
__global__ __launch_bounds__(256)
void reduce_xproj(const float* __restrict__ P, float* __restrict__ xdbl,
                  ushort_t* __restrict__ dtlo)
{
    const int row = blockIdx.x;
    const int col = threadIdx.x;
    float s = 0.f;
    #pragma unroll
    for(int z=0; z<8; z++)
        s += P[(size_t)z*MROWS*256 + (size_t)row*256 + col];
    if (col < 160) xdbl[(size_t)row*160 + col] = s;
    if (col < DTRANK) dtlo[(size_t)row*DTRANK + col] = f2bf(s);
}

// depthwise causal conv (k=4) + bias + silu, bf16 in/out
__global__ __launch_bounds__(256)
void conv_silu_bf(const ushort_t* __restrict__ xb, const float* __restrict__ w,
                  const float* __restrict__ bias, ushort_t* __restrict__ xc)
{
    const int gid = blockIdx.x*256 + threadIdx.x;
    const int d = gid & (DINNER-1);
    const int t = gid >> 12;
    const int l = t & (L_-1);
    float s = bias[d];
    #pragma unroll
    for(int j=0;j<DCONV;j++){
        const int ll = l - (DCONV-1) + j;
        if (ll >= 0)
            s = fmaf(bf2f(xb[(size_t)(t-(DCONV-1)+j)*DINNER + d]), w[d*DCONV+j], s);
    }
    xc[(size_t)t*DINNER + d] = f2bf(s * sigmoidf_(s));
}

// ---- chunked scan, one thread per channel d, 16 states in registers ----
__global__ __launch_bounds__(256)
void scan_phase1(const ushort_t* __restrict__ dt_bf,
                 const ushort_t* __restrict__ xconv,
                 const float* __restrict__ xdbl,
                 const float* __restrict__ A_log,
                 float* __restrict__ sc_h, float* __restrict__ sc_S)
{
    const int tid = threadIdx.x;
    const int d = blockIdx.x*256 + tid;
    const int chunk = blockIdx.y;
    const int b = blockIdx.z;
    const int l0 = chunk*CLEN;

    __shared__ float Bs[CLEN][DSTATE];
    for(int i=tid; i<CLEN*DSTATE; i+=256){
        const int row = i >> 4, n = i & 15;
        Bs[row][n] = xdbl[(size_t)(b*L_ + l0 + row)*160 + DTRANK + n];
    }
    float negA[DSTATE];
    #pragma unroll
    for(int n=0;n<DSTATE;n++) negA[n] = -expf(A_log[d*DSTATE + n]) * LOG2E;
    __syncthreads();

    float h[DSTATE], S[DSTATE];
    #pragma unroll
    for(int n=0;n<DSTATE;n++){ h[n]=0.f; S[n]=0.f; }

    size_t idx = (size_t)(b*L_ + l0)*DINNER + d;
    float dt_c = bf2f(dt_bf[idx]);
    float xv_c = bf2f(xconv[idx]);
    for(int l=0;l<CLEN;l++){
        float dt_n = 0.f, xv_n = 0.f;
        if (l+1 < CLEN){
            dt_n = bf2f(dt_bf[idx + DINNER]);
            xv_n = bf2f(xconv[idx + DINNER]);
        }
        const float dx = dt_c * xv_c;
        #pragma unroll
        for(int n=0;n<DSTATE;n++){
            const float t = dt_c * negA[n];
            S[n] += t;
            h[n] = fmaf(h[n], fast_exp2(t), dx*Bs[l][n]);
        }
        dt_c = dt_n; xv_c = xv_n;
        idx += DINNER;
    }
    const size_t o = (size_t)(b*NCHUNK + chunk)*DSTATE*DINNER + d;
    #pragma unroll
    for(int n=0;n<DSTATE;n++){
        sc_h[o + (size_t)n*DINNER] = h[n];
        sc_S[o + (size_t)n*DINNER] = S[n];
    }
}

__global__ __launch_bounds__(256)
void scan_phase2(float* __restrict__ sc_h, const float* __restrict__ sc_S)
{
    const int gid = blockIdx.x*256 + threadIdx.x;
    const int b = gid / (DSTATE*DINNER);
    const int rem = gid - b*DSTATE*DINNER;
    const size_t base = (size_t)b*NCHUNK*DSTATE*DINNER + rem;
    float H = 0.f;
    #pragma unroll
    for(int c=0;c<NCHUNK;c++){
        const size_t idx = base + (size_t)c*DSTATE*DINNER;
        const float he = sc_h[idx];
        const float S  = sc_S[idx];
        sc_h[idx] = H;
        H = fmaf(fast_exp2(S), H, he);
    }
}

__global__ __launch_bounds__(256)
void scan_phase3(const ushort_t* __restrict__ dt_bf,
                 const ushort_t* __restrict__ xconv,
                 const float* __restrict__ xdbl,
                 const ushort_t* __restrict__ z_bf,
                 const float* __restrict__ A_log,
                 const float* __restrict__ Dvec,
                 const float* __restrict__ sc_h,
                 ushort_t* __restrict__ y_bf)
{
    const int tid = threadIdx.x;
    const int d = blockIdx.x*256 + tid;
    const int chunk = blockIdx.y;
    const int b = blockIdx.z;
    const int l0 = chunk*CLEN;

    __shared__ float BCs[CLEN][2*DSTATE];
    for(int i=tid; i<CLEN*2*DSTATE; i+=256){
        const int row = i >> 5, c = i & 31;
        BCs[row][c] = xdbl[(size_t)(b*L_ + l0 + row)*160 + DTRANK + c];
    }
    float negA[DSTATE];
    #pragma unroll
    for(int n=0;n<DSTATE;n++) negA[n] = -expf(A_log[d*DSTATE + n]) * LOG2E;
    const float Dv = Dvec[d];
    float h[DSTATE];
    const size_t o = (size_t)(b*NCHUNK + chunk)*DSTATE*DINNER + d;
    #pragma unroll
    for(int n=0;n<DSTATE;n++) h[n] = sc_h[o + (size_t)n*DINNER];
    __syncthreads();

    size_t idx = (size_t)(b*L_ + l0)*DINNER + d;
    float dt_c = bf2f(dt_bf[idx]);
    float xv_c = bf2f(xconv[idx]);
    float zv_c = bf2f(z_bf[idx]);
    for(int l=0;l<CLEN;l++){
        float dt_n = 0.f, xv_n = 0.f, zv_n = 0.f;
        if (l+1 < CLEN){
            dt_n = bf2f(dt_bf[idx + DINNER]);
            xv_n = bf2f(xconv[idx + DINNER]);
            zv_n = bf2f(z_bf[idx + DINNER]);
        }
        const float dx = dt_c * xv_c;
        float y = 0.f;
        #pragma unroll
        for(int n=0;n<DSTATE;n++){
            const float t = dt_c * negA[n];
            h[n] = fmaf(h[n], fast_exp2(t), dx*BCs[l][n]);
            y = fmaf(h[n], BCs[l][DSTATE+n], y);
        }
        const float g = zv_c * sigmoidf_(zv_c);
        y_bf[idx] = f2bf(fmaf(xv_c, Dv, y) * g);
        dt_c = dt_n; xv_c = xv_n; zv_c = zv_n;
        idx += DINNER;
    }
}

extern "C" void kernel_launch(void* const* d_in, const int* in_sizes, int n_in,
                              void* d_out, int out_size, void* d_ws, size_t ws_size,
                              hipStream_t stream) {
    const float* hs      = (const float*)d_in[0];
    const float* w_in    = (const float*)d_in[1];
    const float* w_conv  = (const float*)d_in[2];
    const float* b_conv  = (const float*)d_in[3];
    const float* w_xproj = (const float*)d_in[4];
    const float* w_dt    = (const float*)d_in[5];
    const float* b_dt    = (const float*)d_in[6];
    const float* w_out   = (const float*)d_in[7];
    const float* A_log   = (const float*)d_in[8];
    const float* Dvec    = (const float*)d_in[9];
    float* out = (float*)d_out;

    // workspace layout (peak 176 MiB):
    // [0,32M)    x_bf -> after conv: xdbl@0, wx_bf@4M, dtlo@6M, wdt@7M, sc_h@8M(16M)
    // [32M,64M)  z_bf               (live to phase3)
    // [64M,96M)  xconv              (live to phase3)
    // [96M,128M) wi_bf -> after in_proj: dt_bf
    // [128M,144M) hs_bf -> after in_proj: sc_S -> after phase2: wo_bf
    // [144M,176M) y_bf  (also x_proj split-K partials, dead before phase3)
    char* base = (char*)d_ws;
    ushort_t* x_bf   = (ushort_t*)(base);
    float*    xdbl   = (float*)   (base);
    ushort_t* wx_bf  = (ushort_t*)(base + (4u<<20));
    ushort_t* dtlo_bf= (ushort_t*)(base + (6u<<20));
    ushort_t* wdt_bf = (ushort_t*)(base + (7u<<20));
    float*    sc_h   = (float*)   (base + (8u<<20));
    ushort_t* z_bf   = (ushort_t*)(base + (32u<<20));
    ushort_t* xconv  = (ushort_t*)(base + (64u<<20));
    ushort_t* wi_bf  = (ushort_t*)(base + (96u<<20));
    ushort_t* dt_bf  = (ushort_t*)(base + (96u<<20));
    ushort_t* hs_bf  = (ushort_t*)(base + (128u<<20));
    float*    sc_S   = (float*)   (base + (128u<<20));
    ushort_t* wo_bf  = (ushort_t*)(base + (128u<<20));
    float*    xp_par = (float*)   (base + (144u<<20));  // 8*4096*256*4 = 32 MiB
    ushort_t* y_bf   = (ushort_t*)(base + (144u<<20));

    dim3 blk(256);
    dim3 blk5(512);

    // convert activations + in_proj weights to bf16
    cvt_bf16<<<dim3(MROWS*DMODEL/4/256), blk, 0, stream>>>(hs, hs_bf, MROWS*DMODEL/4);
    cvt_bf16<<<dim3(2*DINNER*DMODEL/4/256), blk, 0, stream>>>(w_in, wi_bf, 2*DINNER*DMODEL/4);

    // fused in_proj (256^2 v3 anti-phase schedule): N=8192, split x / z halves
    gemm_256<1,1,0><<<dim3(MROWS/256, 2*DINNER/256), blk5, 0, stream>>>(
        hs_bf, DMODEL, wi_bf, DMODEL, x_bf, z_bf, DINNER, DMODEL);

    // conv + silu -> xconv bf16 (x_bf region becomes free after this)
    conv_silu_bf<<<dim3((size_t)MROWS*DINNER/256), blk, 0, stream>>>(x_bf, w_conv, b_conv, xconv);

    // x_proj: split-K x 8 into f32 partials, then reduce (+fused dtlo cvt)
    cvt_pad256<<<dim3(256*4096/4/256), blk, 0, stream>>>(w_xproj, wx_bf);
    gemm_mfma<0,0,0,1><<<dim3(MROWS/128, 2, 8), blk, 0, stream>>>(
        xconv, DINNER, wx_bf, DINNER, xp_par, nullptr, 256, DINNER/8, nullptr);
    reduce_xproj<<<dim3(MROWS), blk, 0, stream>>>(xp_par, xdbl, dtlo_bf);

    // dt_proj + bias + softplus -> dt_bf (overwrites dead wi_bf region)
    cvt_bf16<<<dim3(DINNER*DTRANK/4/256), blk, 0, stream>>>(w_dt, wdt_bf, DINNER*DTRANK/4);
    gemm_mfma<1,1,0,0><<<dim3(MROWS/128, DINNER/128), blk, 0, stream>>>(
        dtlo_bf, DTRANK, wdt_bf, DTRANK, dt_bf, nullptr, DINNER, DTRANK, b_dt);

    // chunked selective scan (thread-per-channel, coalesced)
    dim3 sgrid(DINNER/256, NCHUNK, B_);
    scan_phase1<<<sgrid, blk, 0, stream>>>(dt_bf, xconv, xdbl, A_log, sc_h, sc_S);
    scan_phase2<<<dim3(B_*DSTATE*DINNER/256), blk, 0, stream>>>(sc_h, sc_S);

    // w_out conversion (sc_S dead after phase2; reuse its region)
    cvt_bf16<<<dim3(DMODEL*DINNER/4/256), blk, 0, stream>>>(w_out, wo_bf, DMODEL*DINNER/4);

    scan_phase3<<<sgrid, blk, 0, stream>>>(dt_bf, xconv, xdbl, z_bf, A_log, Dvec, sc_h, y_bf);

    // out_proj (128^2 kernel, 512 blocks -> full machine, direct f32 out)
    gemm_mfma<0,0,0,0><<<dim3(MROWS/128, DMODEL/128), blk, 0, stream>>>(
        y_bf, DINNER, wo_bf, DINNER, out, nullptr, DMODEL, DINNER, nullptr);
}